// Round 14
// baseline (1919.068 us; speedup 1.0000x reference)
//
#include <hip/hip_runtime.h>

#define TT   2048
#define BBB  2
#define DDD  1024
#define LLL  4
#define HHH  16
#define VVV  32000
#define HIDR 2730
#define HIDP 2816
#define MMM  (BBB*TT)   // 4096

typedef __bf16 bf16x8 __attribute__((ext_vector_type(8)));
typedef float  f32x4  __attribute__((ext_vector_type(4)));

#define BAR()    asm volatile("s_barrier" ::: "memory")
#define LGKM0()  asm volatile("s_waitcnt lgkmcnt(0)" ::: "memory")
#define VMC(n)   asm volatile("s_waitcnt vmcnt(" #n ")" ::: "memory")
#define SCHED0() __builtin_amdgcn_sched_barrier(0)

__device__ __forceinline__ void gl2lds16(const void* g, void* l) {
  __builtin_amdgcn_global_load_lds((const __attribute__((address_space(1))) void*)g,
                                   (__attribute__((address_space(3))) void*)l, 16, 0, 0);
}

__device__ __forceinline__ f32x4 mfma16(bf16x8 a, bf16x8 b, f32x4 c) {
  return __builtin_amdgcn_mfma_f32_16x16x32_bf16(a, b, c, 0, 0, 0);
}

__device__ __forceinline__ float block_reduce_sum(float v) {
  __shared__ float red[4];
  #pragma unroll
  for (int o = 32; o > 0; o >>= 1) v += __shfl_xor(v, o);
  int w = threadIdx.x >> 6;
  if ((threadIdx.x & 63) == 0) red[w] = v;
  __syncthreads();
  float r = red[0] + red[1] + red[2] + red[3];
  __syncthreads();
  return r;
}

// rmul: physical row = logical row * rmul (for W1/W3 interleave), applied to dst only.
struct QDesc { const float* src; __bf16* dst; int srcR, srcC, dstR, dstC, quant, rmul; };
struct QDescs { QDesc d[29]; };

// ---- weight quantization ----------------------------------------------------
__global__ __launch_bounds__(256) void reduce_abs_kernel(QDescs qd, float* partial) {
  const QDesc e = qd.d[blockIdx.y];
  size_t n4 = ((size_t)e.srcR * e.srcC) >> 2;   // all sizes divisible by 4
  const float4* s4 = (const float4*)e.src;
  float acc = 0.f;
  for (size_t i = (size_t)blockIdx.x * blockDim.x + threadIdx.x; i < n4;
       i += (size_t)gridDim.x * blockDim.x) {
    float4 v = s4[i];
    acc += fabsf(v.x) + fabsf(v.y) + fabsf(v.z) + fabsf(v.w);
  }
  float s = block_reduce_sum(acc);
  if (threadIdx.x == 0) partial[blockIdx.y * 256 + blockIdx.x] = s;
}

__global__ __launch_bounds__(256) void finalize_gamma_kernel(QDescs qd, const float* partial,
                                                             float* gamma) {
  int m = blockIdx.x;
  float v = partial[m * 256 + threadIdx.x];
  float s = block_reduce_sum(v);
  if (threadIdx.x == 0) {
    float n = (float)((size_t)qd.d[m].srcR * qd.d[m].srcC);
    gamma[m] = fmaxf(s / n, 1e-5f);
  }
}

__global__ __launch_bounds__(256) void quant_kernel(QDescs qd, const float* gamma) {
  const QDesc e = qd.d[blockIdx.y];
  float invg = 1.0f / gamma[blockIdx.y];
  int nc8 = e.dstC >> 3;
  for (int row = blockIdx.x; row < e.dstR; row += gridDim.x) {
    const float* srow = e.src + (size_t)row * e.srcC;
    bf16x8* drow = (bf16x8*)(e.dst + (size_t)row * e.rmul * e.dstC);
    bool rok = row < e.srcR;
    for (int c8 = threadIdx.x; c8 < nc8; c8 += 256) {
      int c = c8 * 8;
      float w[8];
      if (rok && c + 8 <= e.srcC) {
        float2 v01 = *(const float2*)(srow + c);
        float2 v23 = *(const float2*)(srow + c + 2);
        float2 v45 = *(const float2*)(srow + c + 4);
        float2 v67 = *(const float2*)(srow + c + 6);
        w[0] = v01.x; w[1] = v01.y; w[2] = v23.x; w[3] = v23.y;
        w[4] = v45.x; w[5] = v45.y; w[6] = v67.x; w[7] = v67.y;
      } else {
        #pragma unroll
        for (int j = 0; j < 8; ++j) w[j] = (rok && c + j < e.srcC) ? srow[c + j] : 0.f;
      }
      bf16x8 o;
      #pragma unroll
      for (int j = 0; j < 8; ++j) {
        if (e.quant) {
          float q = rintf(w[j] * invg);
          o[j] = (__bf16)fminf(1.f, fmaxf(-1.f, q));
        } else {
          o[j] = (__bf16)w[j];
        }
      }
      drow[c8] = o;
    }
  }
}

// ---- misc small kernels -----------------------------------------------------
__global__ void rope_table_kernel(float* cosT, float* sinT) {
  int i = blockIdx.x * 256 + threadIdx.x;   // T*32 entries
  int t = i >> 5, j = i & 31;
  float inv = powf(10000.0f, -(float)j * (1.0f / 32.0f));
  float ang = (float)t * inv;
  cosT[i] = cosf(ang);
  sinT[i] = sinf(ang);
}

__global__ void idx_mode_kernel(const void* idxv, int* flag) {
  const long long* p = (const long long*)idxv;
  int good = 1;
  for (int i = threadIdx.x; i < (BBB * TT) / 2; i += 256) {
    long long v = p[i];
    if (v < 0 || v >= VVV) good = 0;
  }
  unsigned long long b = __ballot(good);
  __shared__ int r[4];
  if ((threadIdx.x & 63) == 0) r[threadIdx.x >> 6] = (b == ~0ULL) ? 1 : 0;
  __syncthreads();
  if (threadIdx.x == 0) flag[0] = r[0] & r[1] & r[2] & r[3];
}

__global__ __launch_bounds__(256) void gather_kernel(const float* emb, const void* idxv,
                                                     const int* flag, float* x) {
  int tok = blockIdx.x;
  long long id;
  if (flag[0]) id = ((const long long*)idxv)[tok];
  else         id = (long long)((const int*)idxv)[tok];
  const float4* src = (const float4*)(emb + (size_t)id * DDD);
  float4* dst = (float4*)(x + (size_t)tok * DDD);
  dst[threadIdx.x] = src[threadIdx.x];
}

__global__ __launch_bounds__(256) void rmsnorm_kernel(const float* x, const float* g, __bf16* h) {
  int tok = blockIdx.x;
  const float4* xr = (const float4*)(x + (size_t)tok * DDD);
  float4 v = xr[threadIdx.x];
  float ss = v.x * v.x + v.y * v.y + v.z * v.z + v.w * v.w;
  float tot = block_reduce_sum(ss);
  float r = rsqrtf(tot * (1.0f / (float)DDD) + 1e-6f);
  const float4* gr = (const float4*)g;
  float4 gv = gr[threadIdx.x];
  union { __bf16 o[4]; uint2 u2; } pk;
  pk.o[0] = (__bf16)(v.x * r * gv.x);
  pk.o[1] = (__bf16)(v.y * r * gv.y);
  pk.o[2] = (__bf16)(v.z * r * gv.z);
  pk.o[3] = (__bf16)(v.w * r * gv.w);
  *(uint2*)((char*)h + ((size_t)tok * DDD + threadIdx.x * 4) * 2) = pk.u2;
}

// ---- RoPE + repack: qkv(B,T,3072) -> Qp,Kp (B,H,T,HD) roped; Vp (B,H,HD,T)
__global__ __launch_bounds__(256) void repack_kernel(const __bf16* qkv, const float* cosT,
                                                     const float* sinT, __bf16* Qp, __bf16* Kp,
                                                     __bf16* Vp) {
  int bh = blockIdx.y;
  int b = bh >> 4, h = bh & 15;
  int t0 = blockIdx.x * 64;
  int r = threadIdx.x >> 2;
  int cq = (threadIdx.x & 3) * 16;
  int t = t0 + r;
  __shared__ __bf16 vt[64][72];
  size_t src = ((size_t)b * TT + t) * 3072 + h * 64;

  #pragma unroll
  for (int which = 0; which < 2; ++which) {
    const __bf16* inp = qkv + (which ? 1024 : 0);
    __bf16* outp = which ? Kp : Qp;
    __bf16 val[16], par[16];
    *(bf16x8*)&val[0] = *(const bf16x8*)(inp + src + cq);
    *(bf16x8*)&val[8] = *(const bf16x8*)(inp + src + cq + 8);
    *(bf16x8*)&par[0] = *(const bf16x8*)(inp + src + (cq ^ 32));
    *(bf16x8*)&par[8] = *(const bf16x8*)(inp + src + (cq ^ 32) + 8);
    __bf16 o[16];
    #pragma unroll
    for (int i2 = 0; i2 < 16; ++i2) {
      int d = cq + i2;
      float c = cosT[t * 32 + (d & 31)];
      float s = sinT[t * 32 + (d & 31)];
      float x0 = (float)val[i2], xp = (float)par[i2];
      float res = (d < 32) ? (x0 * c - xp * s) : (x0 * c + xp * s);
      o[i2] = (__bf16)res;
    }
    *(bf16x8*)(outp + ((size_t)bh * TT + t) * 64 + cq) = *(bf16x8*)&o[0];
    *(bf16x8*)(outp + ((size_t)bh * TT + t) * 64 + cq + 8) = *(bf16x8*)&o[8];
  }

  bf16x8 v0 = *(const bf16x8*)(qkv + 2048 + src + cq);
  bf16x8 v1 = *(const bf16x8*)(qkv + 2048 + src + cq + 8);
  #pragma unroll
  for (int i2 = 0; i2 < 8; ++i2) {
    vt[r][cq + i2] = v0[i2];
    vt[r][cq + 8 + i2] = v1[i2];
  }
  __syncthreads();
  __bf16 ov[16];
  #pragma unroll
  for (int i2 = 0; i2 < 16; ++i2) ov[i2] = vt[cq + i2][r];
  *(bf16x8*)(Vp + ((size_t)bh * 64 + r) * TT + t0 + cq) = *(bf16x8*)&ov[0];
  *(bf16x8*)(Vp + ((size_t)bh * 64 + r) * TT + t0 + cq + 8) = *(bf16x8*)&ov[8];
}

// ---- flash attention: block = (128 q-rows, one (b,h)) -----------------------
// exp2-domain online softmax + T13 defer-max + double-buffered K/V staging.
// Complementary block ordering: block i (i<256) -> qt=qp (light), block i+256
// -> qt=15-qp (heavy); sequential dispatch pairs them per CU (~34 tiles/CU).
__global__ __launch_bounds__(256) void attn_kernel(const __bf16* __restrict__ Qp,
                                                   const __bf16* __restrict__ Kp,
                                                   const __bf16* __restrict__ Vp,
                                                   __bf16* __restrict__ y) {
  int i = blockIdx.y * gridDim.x + blockIdx.x;   // 512 blocks
  int bh = i & 31;
  int qp = (i >> 5) & 7;
  int qt = (i >> 8) ? (15 - qp) : qp;

  int b = bh >> 4, h = bh & 15;
  int lane = threadIdx.x & 63, wave = threadIdx.x >> 6;
  int l15 = lane & 15, l4 = lane >> 4;
  int q0 = qt * 128;
  const int ssw = (l15 & 7);
  const int csw = ((lane & 7) ^ (lane >> 3)) * 8;
  const float SC = 0.125f * 1.44269504f;   // scale * log2(e)

  __shared__ __bf16 Ks[2][64 * 64];
  __shared__ __bf16 Vts[2][64 * 64];
  __shared__ __bf16 Ps[4][32 * 64];

  const __bf16* Qb = Qp + (size_t)bh * TT * 64;
  bf16x8 qf[2][2];
  #pragma unroll
  for (int mf = 0; mf < 2; ++mf)
    #pragma unroll
    for (int kk = 0; kk < 2; ++kk)
      qf[mf][kk] = *(const bf16x8*)(Qb + (size_t)(q0 + wave * 32 + mf * 16 + l15) * 64 +
                                    kk * 32 + l4 * 8);

  const f32x4 z4 = {0.f, 0.f, 0.f, 0.f};
  f32x4 acc[2][4];
  float mrow[2][4], lrow[2][4];
  #pragma unroll
  for (int mf = 0; mf < 2; ++mf)
    #pragma unroll
    for (int j = 0; j < 4; ++j) { mrow[mf][j] = -1e30f; lrow[mf][j] = 0.f; }
  #pragma unroll
  for (int mf = 0; mf < 2; ++mf)
    #pragma unroll
    for (int df = 0; df < 4; ++df) acc[mf][df] = z4;

  auto stage = [&](int kt, int buf) {
    int k0 = kt * 64;
    #pragma unroll
    for (int i2 = 0; i2 < 2; ++i2) {
      int rbase = wave * 16 + i2 * 8;
      int row = rbase + (lane >> 3);
      gl2lds16(Kp + ((size_t)bh * TT + k0 + row) * 64 + csw, &Ks[buf][rbase * 64]);
      gl2lds16(Vp + ((size_t)bh * 64 + row) * TT + k0 + csw, &Vts[buf][rbase * 64]);
    }
  };

  int nkt = q0 / 64 + 2;
  stage(0, 0);
  __syncthreads();

  for (int kt = 0; kt < nkt; ++kt) {
    int k0 = kt * 64;
    int cur = kt & 1;
    if (kt + 1 < nkt) stage(kt + 1, cur ^ 1);
    const __bf16* KsC = Ks[cur];
    const __bf16* VtsC = Vts[cur];

    f32x4 s[2][4];
    #pragma unroll
    for (int mf = 0; mf < 2; ++mf)
      #pragma unroll
      for (int nf = 0; nf < 4; ++nf) s[mf][nf] = z4;
    __builtin_amdgcn_s_setprio(1);
    #pragma unroll
    for (int kk = 0; kk < 2; ++kk) {
      int slot = ((kk * 4 + l4) ^ ssw) * 8;
      bf16x8 kf[4];
      #pragma unroll
      for (int nf = 0; nf < 4; ++nf)
        kf[nf] = *(const bf16x8*)&KsC[(nf * 16 + l15) * 64 + slot];
      #pragma unroll
      for (int mf = 0; mf < 2; ++mf)
        #pragma unroll
        for (int nf = 0; nf < 4; ++nf) s[mf][nf] = mfma16(qf[mf][kk], kf[nf], s[mf][nf]);
    }
    __builtin_amdgcn_s_setprio(0);

    bool domask = (k0 + 63 > q0);
    #pragma unroll
    for (int mf = 0; mf < 2; ++mf) {
      int qrowb = q0 + wave * 32 + mf * 16 + l4 * 4;
      #pragma unroll
      for (int nf = 0; nf < 4; ++nf) {
        int kg = k0 + nf * 16 + l15;
        #pragma unroll
        for (int j = 0; j < 4; ++j) {
          float vv = s[mf][nf][j] * SC;
          if (domask && kg > qrowb + j) vv = -1e30f;
          s[mf][nf][j] = vv;
        }
      }
    }

    // tile-row maxima (log2 domain)
    float mx_[2][4];
    float exm = -1e30f;
    #pragma unroll
    for (int mf = 0; mf < 2; ++mf)
      #pragma unroll
      for (int j = 0; j < 4; ++j) {
        float mx = fmaxf(fmaxf(s[mf][0][j], s[mf][1][j]), fmaxf(s[mf][2][j], s[mf][3][j]));
        mx = fmaxf(mx, __shfl_xor(mx, 1));
        mx = fmaxf(mx, __shfl_xor(mx, 2));
        mx = fmaxf(mx, __shfl_xor(mx, 4));
        mx = fmaxf(mx, __shfl_xor(mx, 8));
        mx_[mf][j] = mx;
        exm = fmaxf(exm, mx - mrow[mf][j]);
      }
    // T13 defer-max: only rescale when some row's max grew by > 8 (log2)
    if (__ballot(exm > 8.0f) != 0ULL) {
      #pragma unroll
      for (int mf = 0; mf < 2; ++mf)
        #pragma unroll
        for (int j = 0; j < 4; ++j) {
          float mnew = fmaxf(mrow[mf][j], mx_[mf][j]);
          float alpha = exp2f(mrow[mf][j] - mnew);
          mrow[mf][j] = mnew;
          lrow[mf][j] *= alpha;
          #pragma unroll
          for (int df = 0; df < 4; ++df) acc[mf][df][j] *= alpha;
        }
    }

    float psum[2][4];
    #pragma unroll
    for (int mf = 0; mf < 2; ++mf)
      #pragma unroll
      for (int j = 0; j < 4; ++j) psum[mf][j] = 0.f;
    #pragma unroll
    for (int mf = 0; mf < 2; ++mf)
      #pragma unroll
      for (int nf = 0; nf < 4; ++nf)
        #pragma unroll
        for (int j = 0; j < 4; ++j) {
          float pp = exp2f(s[mf][nf][j] - mrow[mf][j]);
          psum[mf][j] += pp;
          int prow = mf * 16 + l4 * 4 + j;
          int pcol = nf * 16 + l15;
          Ps[wave][prow * 64 + (pcol ^ ((prow & 7) << 3))] = (__bf16)pp;
        }
    #pragma unroll
    for (int mf = 0; mf < 2; ++mf)
      #pragma unroll
      for (int j = 0; j < 4; ++j) {
        float rs = psum[mf][j];
        rs += __shfl_xor(rs, 1);
        rs += __shfl_xor(rs, 2);
        rs += __shfl_xor(rs, 4);
        rs += __shfl_xor(rs, 8);
        lrow[mf][j] += rs;
      }

    __builtin_amdgcn_s_setprio(1);
    #pragma unroll
    for (int kk = 0; kk < 2; ++kk) {
      int slot = ((kk * 4 + l4) ^ ssw) * 8;
      bf16x8 pf[2], vf[4];
      #pragma unroll
      for (int mf = 0; mf < 2; ++mf)
        pf[mf] = *(const bf16x8*)&Ps[wave][(mf * 16 + l15) * 64 + slot];
      #pragma unroll
      for (int df = 0; df < 4; ++df)
        vf[df] = *(const bf16x8*)&VtsC[(df * 16 + l15) * 64 + slot];
      #pragma unroll
      for (int mf = 0; mf < 2; ++mf)
        #pragma unroll
        for (int df = 0; df < 4; ++df) acc[mf][df] = mfma16(pf[mf], vf[df], acc[mf][df]);
    }
    __builtin_amdgcn_s_setprio(0);
    __syncthreads();   // drains this wave's staging vmcnt + LDS reads; buffers flip
  }

  #pragma unroll
  for (int mf = 0; mf < 2; ++mf)
    #pragma unroll
    for (int j = 0; j < 4; ++j) {
      float inv = 1.0f / lrow[mf][j];
      int qg = q0 + wave * 32 + mf * 16 + l4 * 4 + j;
      size_t base = ((size_t)b * TT + qg) * DDD + h * 64;
      #pragma unroll
      for (int df = 0; df < 4; ++df)
        y[base + df * 16 + l15] = (__bf16)(acc[mf][df][j] * inv);
    }
}

// ---- 128x128 GEMM — double-buffered (stage kt+1 during compute kt) ---------
// MODE 0: bf16 out; MODE 1: f32 += res; MODE 2: f32 out;
// MODE 3: silu-fused (B rows = interleaved W1/W3); out bf16, col = cofs+(c>>1).
template <int MODE>
__global__ __launch_bounds__(256) void gemm_kernel(const __bf16* __restrict__ A,
                                                   const __bf16* __restrict__ Bw, void* Cout,
                                                   const float* Res, const float* gscale,
                                                   int gshift, int cofs,
                                                   int M, int N, int K) {
  __shared__ __bf16 As[2][128 * 64];
  __shared__ __bf16 Bs[2][128 * 64];
  int nwg = gridDim.x * gridDim.y;
  int orig = blockIdx.y * gridDim.x + blockIdx.x;
  int qq = nwg >> 3;
  int swz = (orig & 7) * qq + (orig >> 3);
  int bx = swz % gridDim.x, by = swz / gridDim.x;
  const int m0 = bx * 128, n0 = by * 128;

  const int lane = threadIdx.x & 63, wave = threadIdx.x >> 6;
  const int wr = wave >> 1, wc = wave & 1;
  const int l15 = lane & 15, l4 = lane >> 4;
  const int ssw = (l15 & 7);
  const int csw = ((lane & 7) ^ (lane >> 3)) * 8;
  const f32x4 z4 = {0.f, 0.f, 0.f, 0.f};
  f32x4 acc[4][4];
  #pragma unroll
  for (int i = 0; i < 4; ++i)
    #pragma unroll
    for (int j = 0; j < 4; ++j) acc[i][j] = z4;

  auto stage = [&](int kt, int buf) {
    const int kb = kt << 6;
    #pragma unroll
    for (int i = 0; i < 4; ++i) {
      int rbase = wave * 32 + i * 8;
      int row = rbase + (lane >> 3);
      gl2lds16(A + (size_t)(m0 + row) * K + kb + csw, &As[buf][rbase * 64]);
      gl2lds16(Bw + (size_t)(n0 + row) * K + kb + csw, &Bs[buf][rbase * 64]);
    }
  };

  const int nk = K >> 6;
  stage(0, 0);
  __syncthreads();
  for (int kt = 0; kt < nk; ++kt) {
    int cur = kt & 1;
    if (kt + 1 < nk) stage(kt + 1, cur ^ 1);
    #pragma unroll
    for (int kk = 0; kk < 2; ++kk) {
      int slot = ((kk * 4 + l4) ^ ssw) * 8;
      bf16x8 af[4], bfr[4];
      #pragma unroll
      for (int mi = 0; mi < 4; ++mi)
        af[mi] = *(const bf16x8*)&As[cur][(wr * 64 + mi * 16 + l15) * 64 + slot];
      #pragma unroll
      for (int ni = 0; ni < 4; ++ni)
        bfr[ni] = *(const bf16x8*)&Bs[cur][(wc * 64 + ni * 16 + l15) * 64 + slot];
      #pragma unroll
      for (int mi = 0; mi < 4; ++mi)
        #pragma unroll
        for (int ni = 0; ni < 4; ++ni) acc[mi][ni] = mfma16(af[mi], bfr[ni], acc[mi][ni]);
    }
    __syncthreads();   // drains staging vmcnt + LDS reads; buffers flip
  }

  if (MODE == 3) {
    float g1v = gscale[0], g3v = gscale[4];
    __bf16* U = (__bf16*)Cout;
    #pragma unroll
    for (int mi = 0; mi < 4; ++mi)
      #pragma unroll
      for (int ni = 0; ni < 4; ++ni)
        #pragma unroll
        for (int j = 0; j < 4; ++j) {
          int r = m0 + wr * 64 + mi * 16 + l4 * 4 + j;
          int c = n0 + wc * 64 + ni * 16 + l15;
          float v = acc[mi][ni][j];
          float av = v * g1v;                 // valid on even lanes (even c)
          float bv = v * g3v;                 // valid on odd lanes
          float pav = __shfl_xor(av, 1);
          float pbv = __shfl_xor(bv, 1);
          float aa = (lane & 1) ? pav : av;
          float bb = (lane & 1) ? bv : pbv;
          float u = aa / (1.0f + __expf(-aa)) * bb;
          if (!(lane & 1)) U[(size_t)r * HIDP + cofs + (c >> 1)] = (__bf16)u;
        }
    return;
  }

  float sc = gscale ? gscale[n0 >> gshift] : 1.0f;
  #pragma unroll
  for (int mi = 0; mi < 4; ++mi)
    #pragma unroll
    for (int ni = 0; ni < 4; ++ni)
      #pragma unroll
      for (int j = 0; j < 4; ++j) {
        int r = m0 + wr * 64 + mi * 16 + l4 * 4 + j;
        int c = n0 + wc * 64 + ni * 16 + l15;
        size_t off = (size_t)r * N + c;
        float v = acc[mi][ni][j] * sc;
        if (MODE == 0) ((__bf16*)Cout)[off] = (__bf16)v;
        else if (MODE == 1) ((float*)Cout)[off] = Res[off] + v;
        else ((float*)Cout)[off] = v;
      }
}

// ---- 256x256 8-phase GEMM (R4 schedule — frozen) ---------------------------
// MODE 0: bf16 out; MODE 1: f32 += res; MODE 2: f32 out;
// MODE 3: silu-fused (W1/W3 row-interleaved; out bf16 cols cofs+(c>>1)).
template <int MODE>
__global__ __launch_bounds__(512, 2) void gemm256_kernel(const __bf16* __restrict__ A,
                                                         const __bf16* __restrict__ Bw,
                                                         void* Cout, const float* Res,
                                                         const float* gscale, int gshift,
                                                         int M, int N, int K) {
  __shared__ __bf16 AS[2][2][256 * 32];
  __shared__ __bf16 BS[2][2][256 * 32];
  int nwg = gridDim.x * gridDim.y;
  int orig = blockIdx.y * gridDim.x + blockIdx.x;
  int qq = nwg >> 3;
  int swz = (orig & 7) * qq + (orig >> 3);
  int bx = swz % gridDim.x, by = swz / gridDim.x;
  const int m0 = bx * 256, n0 = by * 256;

  const int tid = threadIdx.x;
  const int lane = tid & 63, w = tid >> 6;
  const int wr = w >> 2, wc = w & 3;              // 2x4 wave grid
  const int l15 = lane & 15, l4 = lane >> 4;
  const int lsw = (l15 >> 1) & 3;                 // read-side slot XOR
  const int srow = w * 16 + (lane >> 2);          // staging row (+ i*128)
  const int sslot = ((lane & 3) ^ ((lane >> 3) & 3)) * 8;  // pre-swizzled src col

  f32x4 acc[8][4];
  const f32x4 z4 = {0.f, 0.f, 0.f, 0.f};
  #pragma unroll
  for (int i = 0; i < 8; ++i)
    #pragma unroll
    for (int j = 0; j < 4; ++j) acc[i][j] = z4;

  auto stageA = [&](int b, int kh, int t) {
    const __bf16* g = A + (size_t)(m0 + srow) * K + (size_t)t * 64 + kh * 32 + sslot;
    gl2lds16(g, &AS[b][kh][w * 512]);
    gl2lds16(g + (size_t)128 * K, &AS[b][kh][4096 + w * 512]);
  };
  auto stageB = [&](int b, int kh, int t) {
    const __bf16* g = Bw + (size_t)(n0 + srow) * K + (size_t)t * 64 + kh * 32 + sslot;
    gl2lds16(g, &BS[b][kh][w * 512]);
    gl2lds16(g + (size_t)128 * K, &BS[b][kh][4096 + w * 512]);
  };

  bf16x8 af[4], bq[4];
  auto ldA = [&](int b, int kh, int mh) {
    #pragma unroll
    for (int mi = 0; mi < 4; ++mi) {
      int row = wr * 128 + (mh * 4 + mi) * 16 + l15;
      af[mi] = *(const bf16x8*)&AS[b][kh][row * 32 + ((l4 ^ lsw) * 8)];
    }
  };
  auto ldB = [&](int b, int kh) {
    #pragma unroll
    for (int ni = 0; ni < 4; ++ni) {
      int row = wc * 64 + ni * 16 + l15;
      bq[ni] = *(const bf16x8*)&BS[b][kh][row * 32 + ((l4 ^ lsw) * 8)];
    }
  };
  auto domfma = [&](int mh) {
    __builtin_amdgcn_s_setprio(1);
    #pragma unroll
    for (int mi = 0; mi < 4; ++mi)
      #pragma unroll
      for (int ni = 0; ni < 4; ++ni)
        acc[mh * 4 + mi][ni] = mfma16(af[mi], bq[ni], acc[mh * 4 + mi][ni]);
    __builtin_amdgcn_s_setprio(0);
  };

  const int nk = K >> 6;
  const int niter = nk >> 1;
  // prologue: tile0 fully + tile1 (B0, A0, B1); A1(t1) staged at first ph1
  stageA(0, 0, 0); stageB(0, 0, 0); stageA(0, 1, 0); stageB(0, 1, 0);
  stageB(1, 0, 1); stageA(1, 0, 1); stageB(1, 1, 1);
  VMC(6); SCHED0();
  BAR();

  for (int j = 0; j < niter; ++j) {
    int t1 = 2 * j + 1;
    int t2 = 2 * j + 2; if (t2 > nk - 1) t2 = nk - 1;
    int t3 = 2 * j + 3; if (t3 > nk - 1) t3 = nk - 1;
    // ph1: tile 2j (buf0), kh0, m0
    ldB(0, 0); ldA(0, 0, 0);
    stageA(1, 1, t1);
    BAR(); LGKM0(); SCHED0();
    domfma(0);
    BAR();
    // ph2: kh0, m1
    ldA(0, 0, 1);
    stageB(0, 0, t2);
    BAR(); LGKM0(); SCHED0();
    domfma(1);
    BAR();
    // ph3: kh1, m0
    ldB(0, 1); ldA(0, 1, 0);
    stageA(0, 0, t2);
    BAR(); LGKM0(); SCHED0();
    domfma(0);
    BAR();
    // ph4: kh1, m1  (+vmcnt before stage)
    ldA(0, 1, 1);
    VMC(4); SCHED0();
    stageB(0, 1, t2);
    BAR(); LGKM0(); SCHED0();
    domfma(1);
    BAR();
    // ph5: tile 2j+1 (buf1), kh0, m0
    ldB(1, 0); ldA(1, 0, 0);
    stageA(0, 1, t2);
    BAR(); LGKM0(); SCHED0();
    domfma(0);
    BAR();
    // ph6: kh0, m1
    ldA(1, 0, 1);
    stageB(1, 0, t3);
    BAR(); LGKM0(); SCHED0();
    domfma(1);
    BAR();
    // ph7: kh1, m0
    ldB(1, 1); ldA(1, 1, 0);
    stageA(1, 0, t3);
    BAR(); LGKM0(); SCHED0();
    domfma(0);
    BAR();
    // ph8: kh1, m1  (+vmcnt before stage)
    ldA(1, 1, 1);
    VMC(4); SCHED0();
    stageB(1, 1, t3);
    BAR(); LGKM0(); SCHED0();
    domfma(1);
    BAR();
  }

  if (MODE == 3) {
    float g1v = gscale[0], g3v = gscale[4];
    __bf16* U = (__bf16*)Cout;
    #pragma unroll
    for (int mi = 0; mi < 8; ++mi)
      #pragma unroll
      for (int ni = 0; ni < 4; ++ni)
        #pragma unroll
        for (int j = 0; j < 4; ++j) {
          int r = m0 + wr * 128 + mi * 16 + l4 * 4 + j;
          int c = n0 + wc * 64 + ni * 16 + l15;
          float v = acc[mi][ni][j];
          float av = v * g1v;                 // valid on even lanes (even c)
          float bv = v * g3v;                 // valid on odd lanes
          float pav = __shfl_xor(av, 1);
          float pbv = __shfl_xor(bv, 1);
          float aa = (lane & 1) ? pav : av;
          float bb = (lane & 1) ? bv : pbv;
          float u = aa / (1.0f + __expf(-aa)) * bb;
          if (!(lane & 1)) U[(size_t)r * HIDP + (c >> 1)] = (__bf16)u;
        }
    return;
  }

  float sc = gscale ? gscale[n0 >> gshift] : 1.0f;
  #pragma unroll
  for (int mi = 0; mi < 8; ++mi)
    #pragma unroll
    for (int ni = 0; ni < 4; ++ni)
      #pragma unroll
      for (int j = 0; j < 4; ++j) {
        int r = m0 + wr * 128 + mi * 16 + l4 * 4 + j;
        int c = n0 + wc * 64 + ni * 16 + l15;
        size_t off = (size_t)r * N + c;
        float v = acc[mi][ni][j] * sc;
        if (MODE == 0) ((__bf16*)Cout)[off] = (__bf16)v;
        else if (MODE == 1) ((float*)Cout)[off] = Res[off] + v;
        else ((float*)Cout)[off] = v;
      }
}

// -----------------------------------------------------------------------------
extern "C" void kernel_launch(void* const* d_in, const int* in_sizes, int n_in,
                              void* d_out, int out_size, void* d_ws, size_t ws_size,
                              hipStream_t stream) {
  (void)in_sizes; (void)n_in; (void)out_size; (void)ws_size;
  const float* emb = (const float*)d_in[0];
  const float* Wq  = (const float*)d_in[1];
  const float* Wk  = (const float*)d_in[2];
  const float* Wv  = (const float*)d_in[3];
  const float* Wo  = (const float*)d_in[4];
  const float* W1  = (const float*)d_in[5];
  const float* W3  = (const float*)d_in[6];
  const float* W2  = (const float*)d_in[7];
  const float* g1  = (const float*)d_in[8];
  const float* g2  = (const float*)d_in[9];
  const float* gf  = (const float*)d_in[10];
  const float* Wlm = (const float*)d_in[11];
  const void*  idx = d_in[12];
  float* out = (float*)d_out;

  char* p = (char*)d_ws;
  auto take = [&](size_t bytes) -> char* {
    char* r = p;
    p += (bytes + 255) & ~(size_t)255;
    return r;
  };
  __bf16* WqkvQ = (__bf16*)take((size_t)LLL * 3072 * DDD * 2);
  __bf16* WoQ  = (__bf16*)take((size_t)LLL * DDD * DDD * 2);
  __bf16* W13Q = (__bf16*)take((size_t)LLL * 2 * HIDP * DDD * 2);
  __bf16* W2Q  = (__bf16*)take((size_t)LLL * DDD * HIDP * 2);
  __bf16* WlmB = (__bf16*)take((size_t)VVV * DDD * 2);
  float*  xbuf = (float*)take((size_t)MMM * DDD * 4);
  __bf16* hbuf = (__bf16*)take((size_t)MMM * DDD * 2);
  char*   S    = take(69206016);
  float*  cosT = (float*)take((size_t)TT * 32 * 4);
  float*  sinT = (float*)take((size_t)TT * 32 * 4);
  float*  gamma = (float*)take(128);
  float*  partial = (float*)take(29 * 256 * 4);
  int*    flag = (int*)take(256);

  // attn-phase layout in S
  __bf16* qkv = (__bf16*)(S);                 // 4096x3072 bf16 = 25165824 B
  __bf16* Qp  = (__bf16*)(S + 25165824);
  __bf16* Kp  = (__bf16*)(S + 33554432);
  __bf16* Vp  = (__bf16*)(S + 41943040);
  // mlp-phase layout in S
  __bf16* ub  = (__bf16*)(S + 46137344);      // 4096x2816 (written by fused W13)

  QDescs qd;
  for (int l = 0; l < LLL; ++l) {
    qd.d[l * 4 + 0] = QDesc{Wq + (size_t)l * DDD * DDD,
                            WqkvQ + (size_t)l * 3072 * DDD, DDD, DDD, DDD, DDD, 1, 1};
    qd.d[l * 4 + 1] = QDesc{Wk + (size_t)l * DDD * DDD,
                            WqkvQ + (size_t)l * 3072 * DDD + (size_t)DDD * DDD,
                            DDD, DDD, DDD, DDD, 1, 1};
    qd.d[l * 4 + 2] = QDesc{Wv + (size_t)l * DDD * DDD,
                            WqkvQ + (size_t)l * 3072 * DDD + (size_t)2 * DDD * DDD,
                            DDD, DDD, DDD, DDD, 1, 1};
    qd.d[l * 4 + 3] = QDesc{Wo + (size_t)l * DDD * DDD, WoQ + (size_t)l * DDD * DDD,
                            DDD, DDD, DDD, DDD, 1, 1};
    // W1 -> even physical rows (2i), W3 -> odd physical rows (2i+1)
    qd.d[16 + l] = QDesc{W1 + (size_t)l * HIDR * DDD,
                         W13Q + (size_t)l * 2 * HIDP * DDD,
                         HIDR, DDD, HIDP, DDD, 1, 2};
    qd.d[20 + l] = QDesc{W3 + (size_t)l * HIDR * DDD,
                         W13Q + (size_t)l * 2 * HIDP * DDD + (size_t)DDD,
                         HIDR, DDD, HIDP, DDD, 1, 2};
    qd.d[24 + l] = QDesc{W2 + (size_t)l * DDD * HIDR, W2Q + (size_t)l * DDD * HIDP,
                         DDD, HIDR, DDD, HIDP, 1, 1};
  }
  qd.d[28] = QDesc{Wlm, WlmB, VVV, DDD, VVV, DDD, 0, 1};

  reduce_abs_kernel<<<dim3(256, 28), 256, 0, stream>>>(qd, partial);
  finalize_gamma_kernel<<<28, 256, 0, stream>>>(qd, partial, gamma);
  quant_kernel<<<dim3(512, 29), 256, 0, stream>>>(qd, gamma);
  rope_table_kernel<<<(TT * 32) / 256, 256, 0, stream>>>(cosT, sinT);
  idx_mode_kernel<<<1, 256, 0, stream>>>(idx, flag);
  gather_kernel<<<MMM, 256, 0, stream>>>(emb, idx, flag, xbuf);

  for (int l = 0; l < LLL; ++l) {
    rmsnorm_kernel<<<MMM, 256, 0, stream>>>(xbuf, g1 + (size_t)l * DDD, hbuf);
    gemm256_kernel<0><<<dim3(16, 12), 512, 0, stream>>>(
        hbuf, WqkvQ + (size_t)l * 3072 * DDD, qkv, nullptr, gamma + l * 4, 10,
        MMM, 3072, DDD);
    repack_kernel<<<dim3(TT / 64, BBB * HHH), 256, 0, stream>>>(qkv, cosT, sinT, Qp, Kp, Vp);
    attn_kernel<<<dim3(TT / 128, BBB * HHH), 256, 0, stream>>>(Qp, Kp, Vp, hbuf);
    gemm_kernel<1><<<dim3(32, 8), 256, 0, stream>>>(hbuf, WoQ + (size_t)l * DDD * DDD, xbuf,
                                                    xbuf, gamma + l * 4 + 3, 30, 0,
                                                    MMM, DDD, DDD);
    rmsnorm_kernel<<<MMM, 256, 0, stream>>>(xbuf, g2 + (size_t)l * DDD, hbuf);
    // W13 hybrid: cols 0..4095 on 256^2 (exactly 256 blocks = 1 round),
    // cols 4096..5631 on 128^2 (384 light blocks, 2/CU co-resident)
    gemm256_kernel<3><<<dim3(16, 16), 512, 0, stream>>>(
        hbuf, W13Q + (size_t)l * 2 * HIDP * DDD, ub, nullptr, gamma + 16 + l, 30,
        MMM, 4096, DDD);
    gemm_kernel<3><<<dim3(32, 12), 256, 0, stream>>>(
        hbuf, W13Q + (size_t)l * 2 * HIDP * DDD + (size_t)4096 * DDD, ub, nullptr,
        gamma + 16 + l, 30, 2048, MMM, 1536, DDD);
    gemm_kernel<1><<<dim3(32, 8), 256, 0, stream>>>(ub, W2Q + (size_t)l * DDD * HIDP, xbuf,
                                                    xbuf, gamma + 24 + l, 30, 0,
                                                    MMM, DDD, HIDP);
  }
  rmsnorm_kernel<<<MMM, 256, 0, stream>>>(xbuf, gf, hbuf);
  gemm256_kernel<2><<<dim3(16, VVV / 256), 512, 0, stream>>>(hbuf, WlmB, out, nullptr, nullptr,
                                                             30, MMM, VVV, DDD);
}

// Round 15
// 1899.432 us; speedup vs baseline: 1.0103x; 1.0103x over previous
//
#include <hip/hip_runtime.h>

#define TT   2048
#define BBB  2
#define DDD  1024
#define LLL  4
#define HHH  16
#define VVV  32000
#define HIDR 2730
#define HIDP 2816
#define MMM  (BBB*TT)   // 4096

typedef __bf16 bf16x8 __attribute__((ext_vector_type(8)));
typedef float  f32x4  __attribute__((ext_vector_type(4)));

#define BAR()    asm volatile("s_barrier" ::: "memory")
#define LGKM0()  asm volatile("s_waitcnt lgkmcnt(0)" ::: "memory")
#define VMC(n)   asm volatile("s_waitcnt vmcnt(" #n ")" ::: "memory")
#define SCHED0() __builtin_amdgcn_sched_barrier(0)

__device__ __forceinline__ void gl2lds16(const void* g, void* l) {
  __builtin_amdgcn_global_load_lds((const __attribute__((address_space(1))) void*)g,
                                   (__attribute__((address_space(3))) void*)l, 16, 0, 0);
}

__device__ __forceinline__ f32x4 mfma16(bf16x8 a, bf16x8 b, f32x4 c) {
  return __builtin_amdgcn_mfma_f32_16x16x32_bf16(a, b, c, 0, 0, 0);
}

__device__ __forceinline__ float block_reduce_sum(float v) {
  __shared__ float red[4];
  #pragma unroll
  for (int o = 32; o > 0; o >>= 1) v += __shfl_xor(v, o);
  int w = threadIdx.x >> 6;
  if ((threadIdx.x & 63) == 0) red[w] = v;
  __syncthreads();
  float r = red[0] + red[1] + red[2] + red[3];
  __syncthreads();
  return r;
}

// rmul: physical row = logical row * rmul (for W1/W3 interleave), applied to dst only.
struct QDesc { const float* src; __bf16* dst; int srcR, srcC, dstR, dstC, quant, rmul; };
struct QDescs { QDesc d[29]; };

// ---- weight quantization ----------------------------------------------------
__global__ __launch_bounds__(256) void reduce_abs_kernel(QDescs qd, float* partial) {
  const QDesc e = qd.d[blockIdx.y];
  size_t n4 = ((size_t)e.srcR * e.srcC) >> 2;   // all sizes divisible by 4
  const float4* s4 = (const float4*)e.src;
  float acc = 0.f;
  for (size_t i = (size_t)blockIdx.x * blockDim.x + threadIdx.x; i < n4;
       i += (size_t)gridDim.x * blockDim.x) {
    float4 v = s4[i];
    acc += fabsf(v.x) + fabsf(v.y) + fabsf(v.z) + fabsf(v.w);
  }
  float s = block_reduce_sum(acc);
  if (threadIdx.x == 0) partial[blockIdx.y * 256 + blockIdx.x] = s;
}

__global__ __launch_bounds__(256) void finalize_gamma_kernel(QDescs qd, const float* partial,
                                                             float* gamma) {
  int m = blockIdx.x;
  float v = partial[m * 256 + threadIdx.x];
  float s = block_reduce_sum(v);
  if (threadIdx.x == 0) {
    float n = (float)((size_t)qd.d[m].srcR * qd.d[m].srcC);
    gamma[m] = fmaxf(s / n, 1e-5f);
  }
}

__global__ __launch_bounds__(256) void quant_kernel(QDescs qd, const float* gamma) {
  const QDesc e = qd.d[blockIdx.y];
  float invg = 1.0f / gamma[blockIdx.y];
  int nc8 = e.dstC >> 3;
  for (int row = blockIdx.x; row < e.dstR; row += gridDim.x) {
    const float* srow = e.src + (size_t)row * e.srcC;
    bf16x8* drow = (bf16x8*)(e.dst + (size_t)row * e.rmul * e.dstC);
    bool rok = row < e.srcR;
    for (int c8 = threadIdx.x; c8 < nc8; c8 += 256) {
      int c = c8 * 8;
      float w[8];
      if (rok && c + 8 <= e.srcC) {
        float2 v01 = *(const float2*)(srow + c);
        float2 v23 = *(const float2*)(srow + c + 2);
        float2 v45 = *(const float2*)(srow + c + 4);
        float2 v67 = *(const float2*)(srow + c + 6);
        w[0] = v01.x; w[1] = v01.y; w[2] = v23.x; w[3] = v23.y;
        w[4] = v45.x; w[5] = v45.y; w[6] = v67.x; w[7] = v67.y;
      } else {
        #pragma unroll
        for (int j = 0; j < 8; ++j) w[j] = (rok && c + j < e.srcC) ? srow[c + j] : 0.f;
      }
      bf16x8 o;
      #pragma unroll
      for (int j = 0; j < 8; ++j) {
        if (e.quant) {
          float q = rintf(w[j] * invg);
          o[j] = (__bf16)fminf(1.f, fmaxf(-1.f, q));
        } else {
          o[j] = (__bf16)w[j];
        }
      }
      drow[c8] = o;
    }
  }
}

// ---- misc small kernels -----------------------------------------------------
__global__ void rope_table_kernel(float* cosT, float* sinT) {
  int i = blockIdx.x * 256 + threadIdx.x;   // T*32 entries
  int t = i >> 5, j = i & 31;
  float inv = powf(10000.0f, -(float)j * (1.0f / 32.0f));
  float ang = (float)t * inv;
  cosT[i] = cosf(ang);
  sinT[i] = sinf(ang);
}

__global__ void idx_mode_kernel(const void* idxv, int* flag) {
  const long long* p = (const long long*)idxv;
  int good = 1;
  for (int i = threadIdx.x; i < (BBB * TT) / 2; i += 256) {
    long long v = p[i];
    if (v < 0 || v >= VVV) good = 0;
  }
  unsigned long long b = __ballot(good);
  __shared__ int r[4];
  if ((threadIdx.x & 63) == 0) r[threadIdx.x >> 6] = (b == ~0ULL) ? 1 : 0;
  __syncthreads();
  if (threadIdx.x == 0) flag[0] = r[0] & r[1] & r[2] & r[3];
}

__global__ __launch_bounds__(256) void gather_kernel(const float* emb, const void* idxv,
                                                     const int* flag, float* x) {
  int tok = blockIdx.x;
  long long id;
  if (flag[0]) id = ((const long long*)idxv)[tok];
  else         id = (long long)((const int*)idxv)[tok];
  const float4* src = (const float4*)(emb + (size_t)id * DDD);
  float4* dst = (float4*)(x + (size_t)tok * DDD);
  dst[threadIdx.x] = src[threadIdx.x];
}

__global__ __launch_bounds__(256) void rmsnorm_kernel(const float* x, const float* g, __bf16* h) {
  int tok = blockIdx.x;
  const float4* xr = (const float4*)(x + (size_t)tok * DDD);
  float4 v = xr[threadIdx.x];
  float ss = v.x * v.x + v.y * v.y + v.z * v.z + v.w * v.w;
  float tot = block_reduce_sum(ss);
  float r = rsqrtf(tot * (1.0f / (float)DDD) + 1e-6f);
  const float4* gr = (const float4*)g;
  float4 gv = gr[threadIdx.x];
  union { __bf16 o[4]; uint2 u2; } pk;
  pk.o[0] = (__bf16)(v.x * r * gv.x);
  pk.o[1] = (__bf16)(v.y * r * gv.y);
  pk.o[2] = (__bf16)(v.z * r * gv.z);
  pk.o[3] = (__bf16)(v.w * r * gv.w);
  *(uint2*)((char*)h + ((size_t)tok * DDD + threadIdx.x * 4) * 2) = pk.u2;
}

// ---- RoPE + repack: qkv(B,T,3072) -> Qp,Kp (B,H,T,HD) roped; Vp (B,H,HD,T)
__global__ __launch_bounds__(256) void repack_kernel(const __bf16* qkv, const float* cosT,
                                                     const float* sinT, __bf16* Qp, __bf16* Kp,
                                                     __bf16* Vp) {
  int bh = blockIdx.y;
  int b = bh >> 4, h = bh & 15;
  int t0 = blockIdx.x * 64;
  int r = threadIdx.x >> 2;
  int cq = (threadIdx.x & 3) * 16;
  int t = t0 + r;
  __shared__ __bf16 vt[64][72];
  size_t src = ((size_t)b * TT + t) * 3072 + h * 64;

  #pragma unroll
  for (int which = 0; which < 2; ++which) {
    const __bf16* inp = qkv + (which ? 1024 : 0);
    __bf16* outp = which ? Kp : Qp;
    __bf16 val[16], par[16];
    *(bf16x8*)&val[0] = *(const bf16x8*)(inp + src + cq);
    *(bf16x8*)&val[8] = *(const bf16x8*)(inp + src + cq + 8);
    *(bf16x8*)&par[0] = *(const bf16x8*)(inp + src + (cq ^ 32));
    *(bf16x8*)&par[8] = *(const bf16x8*)(inp + src + (cq ^ 32) + 8);
    __bf16 o[16];
    #pragma unroll
    for (int i2 = 0; i2 < 16; ++i2) {
      int d = cq + i2;
      float c = cosT[t * 32 + (d & 31)];
      float s = sinT[t * 32 + (d & 31)];
      float x0 = (float)val[i2], xp = (float)par[i2];
      float res = (d < 32) ? (x0 * c - xp * s) : (x0 * c + xp * s);
      o[i2] = (__bf16)res;
    }
    *(bf16x8*)(outp + ((size_t)bh * TT + t) * 64 + cq) = *(bf16x8*)&o[0];
    *(bf16x8*)(outp + ((size_t)bh * TT + t) * 64 + cq + 8) = *(bf16x8*)&o[8];
  }

  bf16x8 v0 = *(const bf16x8*)(qkv + 2048 + src + cq);
  bf16x8 v1 = *(const bf16x8*)(qkv + 2048 + src + cq + 8);
  #pragma unroll
  for (int i2 = 0; i2 < 8; ++i2) {
    vt[r][cq + i2] = v0[i2];
    vt[r][cq + 8 + i2] = v1[i2];
  }
  __syncthreads();
  __bf16 ov[16];
  #pragma unroll
  for (int i2 = 0; i2 < 16; ++i2) ov[i2] = vt[cq + i2][r];
  *(bf16x8*)(Vp + ((size_t)bh * 64 + r) * TT + t0 + cq) = *(bf16x8*)&ov[0];
  *(bf16x8*)(Vp + ((size_t)bh * 64 + r) * TT + t0 + cq + 8) = *(bf16x8*)&ov[8];
}

// ---- flash attention: block = (128 q-rows, one (b,h)) -----------------------
// exp2-domain online softmax + T13 defer-max + double-buffered K/V staging.
// Complementary block ordering: block i (i<256) -> qt=qp (light), block i+256
// -> qt=15-qp (heavy); sequential dispatch pairs them per CU (~34 tiles/CU).
__global__ __launch_bounds__(256) void attn_kernel(const __bf16* __restrict__ Qp,
                                                   const __bf16* __restrict__ Kp,
                                                   const __bf16* __restrict__ Vp,
                                                   __bf16* __restrict__ y) {
  int i = blockIdx.y * gridDim.x + blockIdx.x;   // 512 blocks
  int bh = i & 31;
  int qp = (i >> 5) & 7;
  int qt = (i >> 8) ? (15 - qp) : qp;

  int b = bh >> 4, h = bh & 15;
  int lane = threadIdx.x & 63, wave = threadIdx.x >> 6;
  int l15 = lane & 15, l4 = lane >> 4;
  int q0 = qt * 128;
  const int ssw = (l15 & 7);
  const int csw = ((lane & 7) ^ (lane >> 3)) * 8;
  const float SC = 0.125f * 1.44269504f;   // scale * log2(e)

  __shared__ __bf16 Ks[2][64 * 64];
  __shared__ __bf16 Vts[2][64 * 64];
  __shared__ __bf16 Ps[4][32 * 64];

  const __bf16* Qb = Qp + (size_t)bh * TT * 64;
  bf16x8 qf[2][2];
  #pragma unroll
  for (int mf = 0; mf < 2; ++mf)
    #pragma unroll
    for (int kk = 0; kk < 2; ++kk)
      qf[mf][kk] = *(const bf16x8*)(Qb + (size_t)(q0 + wave * 32 + mf * 16 + l15) * 64 +
                                    kk * 32 + l4 * 8);

  const f32x4 z4 = {0.f, 0.f, 0.f, 0.f};
  f32x4 acc[2][4];
  float mrow[2][4], lrow[2][4];
  #pragma unroll
  for (int mf = 0; mf < 2; ++mf)
    #pragma unroll
    for (int j = 0; j < 4; ++j) { mrow[mf][j] = -1e30f; lrow[mf][j] = 0.f; }
  #pragma unroll
  for (int mf = 0; mf < 2; ++mf)
    #pragma unroll
    for (int df = 0; df < 4; ++df) acc[mf][df] = z4;

  auto stage = [&](int kt, int buf) {
    int k0 = kt * 64;
    #pragma unroll
    for (int i2 = 0; i2 < 2; ++i2) {
      int rbase = wave * 16 + i2 * 8;
      int row = rbase + (lane >> 3);
      gl2lds16(Kp + ((size_t)bh * TT + k0 + row) * 64 + csw, &Ks[buf][rbase * 64]);
      gl2lds16(Vp + ((size_t)bh * 64 + row) * TT + k0 + csw, &Vts[buf][rbase * 64]);
    }
  };

  int nkt = q0 / 64 + 2;
  stage(0, 0);
  __syncthreads();

  for (int kt = 0; kt < nkt; ++kt) {
    int k0 = kt * 64;
    int cur = kt & 1;
    if (kt + 1 < nkt) stage(kt + 1, cur ^ 1);
    const __bf16* KsC = Ks[cur];
    const __bf16* VtsC = Vts[cur];

    f32x4 s[2][4];
    #pragma unroll
    for (int mf = 0; mf < 2; ++mf)
      #pragma unroll
      for (int nf = 0; nf < 4; ++nf) s[mf][nf] = z4;
    __builtin_amdgcn_s_setprio(1);
    #pragma unroll
    for (int kk = 0; kk < 2; ++kk) {
      int slot = ((kk * 4 + l4) ^ ssw) * 8;
      bf16x8 kf[4];
      #pragma unroll
      for (int nf = 0; nf < 4; ++nf)
        kf[nf] = *(const bf16x8*)&KsC[(nf * 16 + l15) * 64 + slot];
      #pragma unroll
      for (int mf = 0; mf < 2; ++mf)
        #pragma unroll
        for (int nf = 0; nf < 4; ++nf) s[mf][nf] = mfma16(qf[mf][kk], kf[nf], s[mf][nf]);
    }
    __builtin_amdgcn_s_setprio(0);

    bool domask = (k0 + 63 > q0);
    #pragma unroll
    for (int mf = 0; mf < 2; ++mf) {
      int qrowb = q0 + wave * 32 + mf * 16 + l4 * 4;
      #pragma unroll
      for (int nf = 0; nf < 4; ++nf) {
        int kg = k0 + nf * 16 + l15;
        #pragma unroll
        for (int j = 0; j < 4; ++j) {
          float vv = s[mf][nf][j] * SC;
          if (domask && kg > qrowb + j) vv = -1e30f;
          s[mf][nf][j] = vv;
        }
      }
    }

    // tile-row maxima (log2 domain)
    float mx_[2][4];
    float exm = -1e30f;
    #pragma unroll
    for (int mf = 0; mf < 2; ++mf)
      #pragma unroll
      for (int j = 0; j < 4; ++j) {
        float mx = fmaxf(fmaxf(s[mf][0][j], s[mf][1][j]), fmaxf(s[mf][2][j], s[mf][3][j]));
        mx = fmaxf(mx, __shfl_xor(mx, 1));
        mx = fmaxf(mx, __shfl_xor(mx, 2));
        mx = fmaxf(mx, __shfl_xor(mx, 4));
        mx = fmaxf(mx, __shfl_xor(mx, 8));
        mx_[mf][j] = mx;
        exm = fmaxf(exm, mx - mrow[mf][j]);
      }
    // T13 defer-max: only rescale when some row's max grew by > 8 (log2)
    if (__ballot(exm > 8.0f) != 0ULL) {
      #pragma unroll
      for (int mf = 0; mf < 2; ++mf)
        #pragma unroll
        for (int j = 0; j < 4; ++j) {
          float mnew = fmaxf(mrow[mf][j], mx_[mf][j]);
          float alpha = exp2f(mrow[mf][j] - mnew);
          mrow[mf][j] = mnew;
          lrow[mf][j] *= alpha;
          #pragma unroll
          for (int df = 0; df < 4; ++df) acc[mf][df][j] *= alpha;
        }
    }

    float psum[2][4];
    #pragma unroll
    for (int mf = 0; mf < 2; ++mf)
      #pragma unroll
      for (int j = 0; j < 4; ++j) psum[mf][j] = 0.f;
    #pragma unroll
    for (int mf = 0; mf < 2; ++mf)
      #pragma unroll
      for (int nf = 0; nf < 4; ++nf)
        #pragma unroll
        for (int j = 0; j < 4; ++j) {
          float pp = exp2f(s[mf][nf][j] - mrow[mf][j]);
          psum[mf][j] += pp;
          int prow = mf * 16 + l4 * 4 + j;
          int pcol = nf * 16 + l15;
          Ps[wave][prow * 64 + (pcol ^ ((prow & 7) << 3))] = (__bf16)pp;
        }
    #pragma unroll
    for (int mf = 0; mf < 2; ++mf)
      #pragma unroll
      for (int j = 0; j < 4; ++j) {
        float rs = psum[mf][j];
        rs += __shfl_xor(rs, 1);
        rs += __shfl_xor(rs, 2);
        rs += __shfl_xor(rs, 4);
        rs += __shfl_xor(rs, 8);
        lrow[mf][j] += rs;
      }

    __builtin_amdgcn_s_setprio(1);
    #pragma unroll
    for (int kk = 0; kk < 2; ++kk) {
      int slot = ((kk * 4 + l4) ^ ssw) * 8;
      bf16x8 pf[2], vf[4];
      #pragma unroll
      for (int mf = 0; mf < 2; ++mf)
        pf[mf] = *(const bf16x8*)&Ps[wave][(mf * 16 + l15) * 64 + slot];
      #pragma unroll
      for (int df = 0; df < 4; ++df)
        vf[df] = *(const bf16x8*)&VtsC[(df * 16 + l15) * 64 + slot];
      #pragma unroll
      for (int mf = 0; mf < 2; ++mf)
        #pragma unroll
        for (int df = 0; df < 4; ++df) acc[mf][df] = mfma16(pf[mf], vf[df], acc[mf][df]);
    }
    __builtin_amdgcn_s_setprio(0);
    __syncthreads();   // drains this wave's staging vmcnt + LDS reads; buffers flip
  }

  #pragma unroll
  for (int mf = 0; mf < 2; ++mf)
    #pragma unroll
    for (int j = 0; j < 4; ++j) {
      float inv = 1.0f / lrow[mf][j];
      int qg = q0 + wave * 32 + mf * 16 + l4 * 4 + j;
      size_t base = ((size_t)b * TT + qg) * DDD + h * 64;
      #pragma unroll
      for (int df = 0; df < 4; ++df)
        y[base + df * 16 + l15] = (__bf16)(acc[mf][df][j] * inv);
    }
}

// ---- 128x128 GEMM — double-buffered (stage kt+1 during compute kt) ---------
template <int MODE>
__global__ __launch_bounds__(256) void gemm_kernel(const __bf16* __restrict__ A,
                                                   const __bf16* __restrict__ Bw, void* Cout,
                                                   const float* Res, const float* gscale,
                                                   int gshift, int M, int N, int K) {
  __shared__ __bf16 As[2][128 * 64];
  __shared__ __bf16 Bs[2][128 * 64];
  int nwg = gridDim.x * gridDim.y;
  int orig = blockIdx.y * gridDim.x + blockIdx.x;
  int qq = nwg >> 3;
  int swz = (orig & 7) * qq + (orig >> 3);
  int bx = swz % gridDim.x, by = swz / gridDim.x;
  const int m0 = bx * 128, n0 = by * 128;

  const int lane = threadIdx.x & 63, wave = threadIdx.x >> 6;
  const int wr = wave >> 1, wc = wave & 1;
  const int l15 = lane & 15, l4 = lane >> 4;
  const int ssw = (l15 & 7);
  const int csw = ((lane & 7) ^ (lane >> 3)) * 8;
  const f32x4 z4 = {0.f, 0.f, 0.f, 0.f};
  f32x4 acc[4][4];
  #pragma unroll
  for (int i = 0; i < 4; ++i)
    #pragma unroll
    for (int j = 0; j < 4; ++j) acc[i][j] = z4;

  auto stage = [&](int kt, int buf) {
    const int kb = kt << 6;
    #pragma unroll
    for (int i = 0; i < 4; ++i) {
      int rbase = wave * 32 + i * 8;
      int row = rbase + (lane >> 3);
      gl2lds16(A + (size_t)(m0 + row) * K + kb + csw, &As[buf][rbase * 64]);
      gl2lds16(Bw + (size_t)(n0 + row) * K + kb + csw, &Bs[buf][rbase * 64]);
    }
  };

  const int nk = K >> 6;
  stage(0, 0);
  __syncthreads();
  for (int kt = 0; kt < nk; ++kt) {
    int cur = kt & 1;
    if (kt + 1 < nk) stage(kt + 1, cur ^ 1);
    #pragma unroll
    for (int kk = 0; kk < 2; ++kk) {
      int slot = ((kk * 4 + l4) ^ ssw) * 8;
      bf16x8 af[4], bfr[4];
      #pragma unroll
      for (int mi = 0; mi < 4; ++mi)
        af[mi] = *(const bf16x8*)&As[cur][(wr * 64 + mi * 16 + l15) * 64 + slot];
      #pragma unroll
      for (int ni = 0; ni < 4; ++ni)
        bfr[ni] = *(const bf16x8*)&Bs[cur][(wc * 64 + ni * 16 + l15) * 64 + slot];
      #pragma unroll
      for (int mi = 0; mi < 4; ++mi)
        #pragma unroll
        for (int ni = 0; ni < 4; ++ni) acc[mi][ni] = mfma16(af[mi], bfr[ni], acc[mi][ni]);
    }
    __syncthreads();   // drains staging vmcnt + LDS reads; buffers flip
  }

  float sc = gscale ? gscale[n0 >> gshift] : 1.0f;
  #pragma unroll
  for (int mi = 0; mi < 4; ++mi)
    #pragma unroll
    for (int ni = 0; ni < 4; ++ni)
      #pragma unroll
      for (int j = 0; j < 4; ++j) {
        int r = m0 + wr * 64 + mi * 16 + l4 * 4 + j;
        int c = n0 + wc * 64 + ni * 16 + l15;
        size_t off = (size_t)r * N + c;
        float v = acc[mi][ni][j] * sc;
        if (MODE == 0) ((__bf16*)Cout)[off] = (__bf16)v;
        else if (MODE == 1) ((float*)Cout)[off] = Res[off] + v;
        else ((float*)Cout)[off] = v;
      }
}

// ---- 256x256 8-phase GEMM (R4 schedule — frozen) ---------------------------
// MODE 0: bf16 out; MODE 1: f32 += res; MODE 2: f32 out;
// MODE 3: silu-fused (W1/W3 row-interleaved; out bf16 N/2 cols into ub).
template <int MODE>
__global__ __launch_bounds__(512, 2) void gemm256_kernel(const __bf16* __restrict__ A,
                                                         const __bf16* __restrict__ Bw,
                                                         void* Cout, const float* Res,
                                                         const float* gscale, int gshift,
                                                         int M, int N, int K) {
  __shared__ __bf16 AS[2][2][256 * 32];
  __shared__ __bf16 BS[2][2][256 * 32];
  int nwg = gridDim.x * gridDim.y;
  int orig = blockIdx.y * gridDim.x + blockIdx.x;
  int qq = nwg >> 3;
  int swz = (orig & 7) * qq + (orig >> 3);
  int bx = swz % gridDim.x, by = swz / gridDim.x;
  const int m0 = bx * 256, n0 = by * 256;

  const int tid = threadIdx.x;
  const int lane = tid & 63, w = tid >> 6;
  const int wr = w >> 2, wc = w & 3;              // 2x4 wave grid
  const int l15 = lane & 15, l4 = lane >> 4;
  const int lsw = (l15 >> 1) & 3;                 // read-side slot XOR
  const int srow = w * 16 + (lane >> 2);          // staging row (+ i*128)
  const int sslot = ((lane & 3) ^ ((lane >> 3) & 3)) * 8;  // pre-swizzled src col

  f32x4 acc[8][4];
  const f32x4 z4 = {0.f, 0.f, 0.f, 0.f};
  #pragma unroll
  for (int i = 0; i < 8; ++i)
    #pragma unroll
    for (int j = 0; j < 4; ++j) acc[i][j] = z4;

  auto stageA = [&](int b, int kh, int t) {
    const __bf16* g = A + (size_t)(m0 + srow) * K + (size_t)t * 64 + kh * 32 + sslot;
    gl2lds16(g, &AS[b][kh][w * 512]);
    gl2lds16(g + (size_t)128 * K, &AS[b][kh][4096 + w * 512]);
  };
  auto stageB = [&](int b, int kh, int t) {
    const __bf16* g = Bw + (size_t)(n0 + srow) * K + (size_t)t * 64 + kh * 32 + sslot;
    gl2lds16(g, &BS[b][kh][w * 512]);
    gl2lds16(g + (size_t)128 * K, &BS[b][kh][4096 + w * 512]);
  };

  bf16x8 af[4], bq[4];
  auto ldA = [&](int b, int kh, int mh) {
    #pragma unroll
    for (int mi = 0; mi < 4; ++mi) {
      int row = wr * 128 + (mh * 4 + mi) * 16 + l15;
      af[mi] = *(const bf16x8*)&AS[b][kh][row * 32 + ((l4 ^ lsw) * 8)];
    }
  };
  auto ldB = [&](int b, int kh) {
    #pragma unroll
    for (int ni = 0; ni < 4; ++ni) {
      int row = wc * 64 + ni * 16 + l15;
      bq[ni] = *(const bf16x8*)&BS[b][kh][row * 32 + ((l4 ^ lsw) * 8)];
    }
  };
  auto domfma = [&](int mh) {
    __builtin_amdgcn_s_setprio(1);
    #pragma unroll
    for (int mi = 0; mi < 4; ++mi)
      #pragma unroll
      for (int ni = 0; ni < 4; ++ni)
        acc[mh * 4 + mi][ni] = mfma16(af[mi], bq[ni], acc[mh * 4 + mi][ni]);
    __builtin_amdgcn_s_setprio(0);
  };

  const int nk = K >> 6;
  const int niter = nk >> 1;
  // prologue: tile0 fully + tile1 (B0, A0, B1); A1(t1) staged at first ph1
  stageA(0, 0, 0); stageB(0, 0, 0); stageA(0, 1, 0); stageB(0, 1, 0);
  stageB(1, 0, 1); stageA(1, 0, 1); stageB(1, 1, 1);
  VMC(6); SCHED0();
  BAR();

  for (int j = 0; j < niter; ++j) {
    int t1 = 2 * j + 1;
    int t2 = 2 * j + 2; if (t2 > nk - 1) t2 = nk - 1;
    int t3 = 2 * j + 3; if (t3 > nk - 1) t3 = nk - 1;
    // ph1: tile 2j (buf0), kh0, m0
    ldB(0, 0); ldA(0, 0, 0);
    stageA(1, 1, t1);
    BAR(); LGKM0(); SCHED0();
    domfma(0);
    BAR();
    // ph2: kh0, m1
    ldA(0, 0, 1);
    stageB(0, 0, t2);
    BAR(); LGKM0(); SCHED0();
    domfma(1);
    BAR();
    // ph3: kh1, m0
    ldB(0, 1); ldA(0, 1, 0);
    stageA(0, 0, t2);
    BAR(); LGKM0(); SCHED0();
    domfma(0);
    BAR();
    // ph4: kh1, m1  (+vmcnt before stage)
    ldA(0, 1, 1);
    VMC(4); SCHED0();
    stageB(0, 1, t2);
    BAR(); LGKM0(); SCHED0();
    domfma(1);
    BAR();
    // ph5: tile 2j+1 (buf1), kh0, m0
    ldB(1, 0); ldA(1, 0, 0);
    stageA(0, 1, t2);
    BAR(); LGKM0(); SCHED0();
    domfma(0);
    BAR();
    // ph6: kh0, m1
    ldA(1, 0, 1);
    stageB(1, 0, t3);
    BAR(); LGKM0(); SCHED0();
    domfma(1);
    BAR();
    // ph7: kh1, m0
    ldB(1, 1); ldA(1, 1, 0);
    stageA(1, 0, t3);
    BAR(); LGKM0(); SCHED0();
    domfma(0);
    BAR();
    // ph8: kh1, m1  (+vmcnt before stage)
    ldA(1, 1, 1);
    VMC(4); SCHED0();
    stageB(1, 1, t3);
    BAR(); LGKM0(); SCHED0();
    domfma(1);
    BAR();
  }

  if (MODE == 3) {
    float g1v = gscale[0], g3v = gscale[4];
    __bf16* U = (__bf16*)Cout;
    int half = N >> 1;
    #pragma unroll
    for (int mi = 0; mi < 8; ++mi)
      #pragma unroll
      for (int ni = 0; ni < 4; ++ni)
        #pragma unroll
        for (int j = 0; j < 4; ++j) {
          int r = m0 + wr * 128 + mi * 16 + l4 * 4 + j;
          int c = n0 + wc * 64 + ni * 16 + l15;
          float v = acc[mi][ni][j];
          float av = v * g1v;                 // valid on even lanes (even c)
          float bv = v * g3v;                 // valid on odd lanes
          float pav = __shfl_xor(av, 1);
          float pbv = __shfl_xor(bv, 1);
          float aa = (lane & 1) ? pav : av;
          float bb = (lane & 1) ? bv : pbv;
          float u = aa / (1.0f + __expf(-aa)) * bb;
          if (!(lane & 1)) U[(size_t)r * half + (c >> 1)] = (__bf16)u;
        }
    return;
  }

  float sc = gscale ? gscale[n0 >> gshift] : 1.0f;
  #pragma unroll
  for (int mi = 0; mi < 8; ++mi)
    #pragma unroll
    for (int ni = 0; ni < 4; ++ni)
      #pragma unroll
      for (int j = 0; j < 4; ++j) {
        int r = m0 + wr * 128 + mi * 16 + l4 * 4 + j;
        int c = n0 + wc * 64 + ni * 16 + l15;
        size_t off = (size_t)r * N + c;
        float v = acc[mi][ni][j] * sc;
        if (MODE == 0) ((__bf16*)Cout)[off] = (__bf16)v;
        else if (MODE == 1) ((float*)Cout)[off] = Res[off] + v;
        else ((float*)Cout)[off] = v;
      }
}

// -----------------------------------------------------------------------------
extern "C" void kernel_launch(void* const* d_in, const int* in_sizes, int n_in,
                              void* d_out, int out_size, void* d_ws, size_t ws_size,
                              hipStream_t stream) {
  (void)in_sizes; (void)n_in; (void)out_size; (void)ws_size;
  const float* emb = (const float*)d_in[0];
  const float* Wq  = (const float*)d_in[1];
  const float* Wk  = (const float*)d_in[2];
  const float* Wv  = (const float*)d_in[3];
  const float* Wo  = (const float*)d_in[4];
  const float* W1  = (const float*)d_in[5];
  const float* W3  = (const float*)d_in[6];
  const float* W2  = (const float*)d_in[7];
  const float* g1  = (const float*)d_in[8];
  const float* g2  = (const float*)d_in[9];
  const float* gf  = (const float*)d_in[10];
  const float* Wlm = (const float*)d_in[11];
  const void*  idx = d_in[12];
  float* out = (float*)d_out;

  char* p = (char*)d_ws;
  auto take = [&](size_t bytes) -> char* {
    char* r = p;
    p += (bytes + 255) & ~(size_t)255;
    return r;
  };
  __bf16* WqkvQ = (__bf16*)take((size_t)LLL * 3072 * DDD * 2);
  __bf16* WoQ  = (__bf16*)take((size_t)LLL * DDD * DDD * 2);
  __bf16* W13Q = (__bf16*)take((size_t)LLL * 2 * HIDP * DDD * 2);
  __bf16* W2Q  = (__bf16*)take((size_t)LLL * DDD * HIDP * 2);
  __bf16* WlmB = (__bf16*)take((size_t)VVV * DDD * 2);
  float*  xbuf = (float*)take((size_t)MMM * DDD * 4);
  __bf16* hbuf = (__bf16*)take((size_t)MMM * DDD * 2);
  char*   S    = take(69206016);
  float*  cosT = (float*)take((size_t)TT * 32 * 4);
  float*  sinT = (float*)take((size_t)TT * 32 * 4);
  float*  gamma = (float*)take(128);
  float*  partial = (float*)take(29 * 256 * 4);
  int*    flag = (int*)take(256);

  // attn-phase layout in S
  __bf16* qkv = (__bf16*)(S);                 // 4096x3072 bf16 = 25165824 B
  __bf16* Qp  = (__bf16*)(S + 25165824);
  __bf16* Kp  = (__bf16*)(S + 33554432);
  __bf16* Vp  = (__bf16*)(S + 41943040);
  // mlp-phase layout in S
  __bf16* ub  = (__bf16*)(S + 46137344);      // 4096x2816 (written by fused W13)

  QDescs qd;
  for (int l = 0; l < LLL; ++l) {
    qd.d[l * 4 + 0] = QDesc{Wq + (size_t)l * DDD * DDD,
                            WqkvQ + (size_t)l * 3072 * DDD, DDD, DDD, DDD, DDD, 1, 1};
    qd.d[l * 4 + 1] = QDesc{Wk + (size_t)l * DDD * DDD,
                            WqkvQ + (size_t)l * 3072 * DDD + (size_t)DDD * DDD,
                            DDD, DDD, DDD, DDD, 1, 1};
    qd.d[l * 4 + 2] = QDesc{Wv + (size_t)l * DDD * DDD,
                            WqkvQ + (size_t)l * 3072 * DDD + (size_t)2 * DDD * DDD,
                            DDD, DDD, DDD, DDD, 1, 1};
    qd.d[l * 4 + 3] = QDesc{Wo + (size_t)l * DDD * DDD, WoQ + (size_t)l * DDD * DDD,
                            DDD, DDD, DDD, DDD, 1, 1};
    // W1 -> even physical rows (2i), W3 -> odd physical rows (2i+1)
    qd.d[16 + l] = QDesc{W1 + (size_t)l * HIDR * DDD,
                         W13Q + (size_t)l * 2 * HIDP * DDD,
                         HIDR, DDD, HIDP, DDD, 1, 2};
    qd.d[20 + l] = QDesc{W3 + (size_t)l * HIDR * DDD,
                         W13Q + (size_t)l * 2 * HIDP * DDD + (size_t)DDD,
                         HIDR, DDD, HIDP, DDD, 1, 2};
    qd.d[24 + l] = QDesc{W2 + (size_t)l * DDD * HIDR, W2Q + (size_t)l * DDD * HIDP,
                         DDD, HIDR, DDD, HIDP, 1, 1};
  }
  qd.d[28] = QDesc{Wlm, WlmB, VVV, DDD, VVV, DDD, 0, 1};

  reduce_abs_kernel<<<dim3(256, 28), 256, 0, stream>>>(qd, partial);
  finalize_gamma_kernel<<<28, 256, 0, stream>>>(qd, partial, gamma);
  quant_kernel<<<dim3(512, 29), 256, 0, stream>>>(qd, gamma);
  rope_table_kernel<<<(TT * 32) / 256, 256, 0, stream>>>(cosT, sinT);
  idx_mode_kernel<<<1, 256, 0, stream>>>(idx, flag);
  gather_kernel<<<MMM, 256, 0, stream>>>(emb, idx, flag, xbuf);

  for (int l = 0; l < LLL; ++l) {
    rmsnorm_kernel<<<MMM, 256, 0, stream>>>(xbuf, g1 + (size_t)l * DDD, hbuf);
    gemm256_kernel<0><<<dim3(16, 12), 512, 0, stream>>>(
        hbuf, WqkvQ + (size_t)l * 3072 * DDD, qkv, nullptr, gamma + l * 4, 10,
        MMM, 3072, DDD);
    repack_kernel<<<dim3(TT / 64, BBB * HHH), 256, 0, stream>>>(qkv, cosT, sinT, Qp, Kp, Vp);
    attn_kernel<<<dim3(TT / 128, BBB * HHH), 256, 0, stream>>>(Qp, Kp, Vp, hbuf);
    gemm_kernel<1><<<dim3(32, 8), 256, 0, stream>>>(hbuf, WoQ + (size_t)l * DDD * DDD, xbuf,
                                                    xbuf, gamma + l * 4 + 3, 30, MMM, DDD, DDD);
    rmsnorm_kernel<<<MMM, 256, 0, stream>>>(xbuf, g2 + (size_t)l * DDD, hbuf);
    gemm256_kernel<3><<<dim3(16, 2 * HIDP / 256), 512, 0, stream>>>(
        hbuf, W13Q + (size_t)l * 2 * HIDP * DDD, ub, nullptr, gamma + 16 + l, 30,
        MMM, 2 * HIDP, DDD);
    gemm_kernel<1><<<dim3(32, 8), 256, 0, stream>>>(ub, W2Q + (size_t)l * DDD * HIDP, xbuf,
                                                    xbuf, gamma + 24 + l, 30, MMM, DDD, HIDP);
  }
  rmsnorm_kernel<<<MMM, 256, 0, stream>>>(xbuf, gf, hbuf);
  gemm256_kernel<2><<<dim3(16, VVV / 256), 512, 0, stream>>>(hbuf, WlmB, out, nullptr, nullptr,
                                                             30, MMM, VVV, DDD);
}